// Round 21
// baseline (81.459 us; speedup 1.0000x reference)
//
#include <hip/hip_runtime.h>
#include <hip/hip_bf16.h>
#include <math.h>

// Problem constants: B=2, T=2048, C=768, H=12, hd=64
#define TSEQ 2048
#define CDIM 768
#define NH   12
#define HD   64

typedef __attribute__((ext_vector_type(8))) short bf16x8;   // 8 bf16 = 4 VGPRs (MFMA A/B frag)
typedef __attribute__((ext_vector_type(4))) float f32x4;    // MFMA C/D frag

union Bf8 { bf16x8 v; __hip_bfloat16 e[8]; };

// ALiBi slopes PRE-SCALED by 1/ln2 (softmax runs in exp2 domain)
__constant__ float c_slopes2[12] = {
    0.72134752f, 0.36067376f, 0.18033688f, 0.09016844f,
    0.04508422f, 0.02254211f, 0.011271055f, 0.0056355275f,
    1.02015692f, 0.72134752f, 0.51007846f, 0.36067376f
};
#define M2 4.3280851f          // 3/ln2  (fixed softmax max = 3, exp2 domain)
#define QSCALE 0.18033688f     // 0.125/ln2
#define EXP2F(x) __builtin_amdgcn_exp2f(x)

__device__ __forceinline__ unsigned pack2(float lo, float hi) {
    union { __hip_bfloat162 b; unsigned u; } cv;
    cv.b = __float22bfloat162_rn(make_float2(lo, hi));
    return cv.u;
}
__device__ __forceinline__ unsigned short bf16bits(float x) {
    union { __hip_bfloat16 b; unsigned short s; } cv;
    cv.b = __float2bfloat16(x);
    return cv.s;
}

#define MFMA16(a, b, c) __builtin_amdgcn_mfma_f32_16x16x32_bf16(a, b, c, 0, 0, 0)

// ---------------- Kernel 1: qk = x @ W^T + b  (M=4096,N=1536,K=768) ----------------
// 128x128 tile, 512 thr = 8 waves (2x4), grid (12,32) = 384 blocks.
// L2 traffic 302MB vs 453MB for the 128x64 tile (measured-equal waves/CU).
// Round-10..12-proven variant, identical Qb/Kt2 epilogue.
__global__ __launch_bounds__(512) void gemm_qk(
    const float* __restrict__ X,
    const float* __restrict__ W,
    const float* __restrict__ bias,
    __hip_bfloat16* __restrict__ Qb,
    __hip_bfloat16* __restrict__ Kt)
{
    __shared__ alignas(16) __hip_bfloat16 As[128][40];
    __shared__ alignas(16) __hip_bfloat16 Bs[128][40];

    const int tid  = threadIdx.x;
    const int lane = tid & 63;
    const int w    = tid >> 6;       // 0..7
    const int lg   = lane >> 4;
    const int lc   = lane & 15;
    const int m0   = blockIdx.y * 128;
    const int n0   = blockIdx.x * 128;
    const int m0w  = (w >> 2) * 64;
    const int n0w  = (w & 3) * 32;

    const int srow = tid >> 2;       // 0..127
    const int scol = (tid & 3) * 8;  // 0,8,16,24

    f32x4 acc[4][2] = {};

    for (int k0 = 0; k0 < CDIM; k0 += 32) {
        __syncthreads();
        {
            const float* xp = X + (size_t)(m0 + srow) * CDIM + k0 + scol;
            const float* wp = W + (size_t)(n0 + srow) * CDIM + k0 + scol;
            float4 a0 = *(const float4*)(xp);
            float4 a1 = *(const float4*)(xp + 4);
            float4 b0 = *(const float4*)(wp);
            float4 b1 = *(const float4*)(wp + 4);
            Bf8 av, bv;
            av.e[0]=__float2bfloat16(a0.x); av.e[1]=__float2bfloat16(a0.y);
            av.e[2]=__float2bfloat16(a0.z); av.e[3]=__float2bfloat16(a0.w);
            av.e[4]=__float2bfloat16(a1.x); av.e[5]=__float2bfloat16(a1.y);
            av.e[6]=__float2bfloat16(a1.z); av.e[7]=__float2bfloat16(a1.w);
            bv.e[0]=__float2bfloat16(b0.x); bv.e[1]=__float2bfloat16(b0.y);
            bv.e[2]=__float2bfloat16(b0.z); bv.e[3]=__float2bfloat16(b0.w);
            bv.e[4]=__float2bfloat16(b1.x); bv.e[5]=__float2bfloat16(b1.y);
            bv.e[6]=__float2bfloat16(b1.z); bv.e[7]=__float2bfloat16(b1.w);
            *(bf16x8*)&As[srow][scol] = av.v;
            *(bf16x8*)&Bs[srow][scol] = bv.v;
        }
        __syncthreads();

        bf16x8 af[4], bfr[2];
        #pragma unroll
        for (int mt = 0; mt < 4; ++mt)
            af[mt] = *(const bf16x8*)&As[m0w + mt*16 + lc][lg*8];
        #pragma unroll
        for (int nt = 0; nt < 2; ++nt)
            bfr[nt] = *(const bf16x8*)&Bs[n0w + nt*16 + lc][lg*8];
        #pragma unroll
        for (int mt = 0; mt < 4; ++mt)
            #pragma unroll
            for (int nt = 0; nt < 2; ++nt)
                acc[mt][nt] = MFMA16(af[mt], bfr[nt], acc[mt][nt]);
    }

    #pragma unroll
    for (int mt = 0; mt < 4; ++mt) {
        #pragma unroll
        for (int nt = 0; nt < 2; ++nt) {
            int n  = n0 + n0w + nt*16 + lc;
            float bv = bias[n];
            #pragma unroll
            for (int r = 0; r < 4; ++r) {
                int m = m0 + m0w + mt*16 + lg*4 + r;
                float v = acc[mt][nt][r] + bv;
                int b = m >> 11, t = m & (TSEQ-1);
                if (n < CDIM) {
                    int h = n >> 6, dd = n & 63;
                    Qb[(((size_t)(b*NH + h))*TSEQ + t)*HD + dd] = __float2bfloat16(v * QSCALE);
                } else {
                    int n2 = n - CDIM;
                    int h = n2 >> 6, dd = n2 & 63;
                    int bh_ = b*NH + h;
                    int kb = t >> 5, tt = t & 31;
                    int j  = ((tt >> 4) << 1) + (dd >> 5);
                    int ln = (((dd >> 3) & 3) << 4) + (tt & 15);
                    Kt[((size_t)(bh_*64 + kb))*2048 + j*512 + ln*8 + (dd & 7)] =
                        __float2bfloat16(v);
                }
            }
        }
    }
}

// ---------------- Kernel 2: vmixt — fused v head-mix + transpose -> Vt2 ----------------
// Block = (b, kb32, head-group of 3); wave g owns t-octet kb*32+g*8..+7; lane = d.
__global__ __launch_bounds__(256) void vmixt(
    const float* __restrict__ XT, const float* __restrict__ vtmp,
    __hip_bfloat16* __restrict__ Vt)
{
    __shared__ float vm[144];
    const int tid = threadIdx.x;
    if (tid < 144) vm[tid] = vtmp[tid];
    __syncthreads();

    // 512 blocks = 8 XCD chunks x 64: id2 consecutive within an XCD chunk
    const int id2 = (blockIdx.x & 7) * 64 + (blockIdx.x >> 3);
    const int ig  = id2 & 3;
    const int kbb = id2 >> 2;
    const int kb  = kbb & 63;
    const int b   = kbb >> 6;
    const int g   = tid >> 6;
    const int dd  = tid & 63;
    const int i0  = ig * 3;

    float acc[3][8];
    #pragma unroll
    for (int i = 0; i < 3; ++i)
        #pragma unroll
        for (int e = 0; e < 8; ++e) acc[i][e] = 0.f;

    const int tbase = kb*32 + g*8;
    #pragma unroll
    for (int e = 0; e < 8; ++e) {
        const float* xp = XT + ((size_t)(b*TSEQ + tbase + e))*CDIM + dd;
        #pragma unroll
        for (int j = 0; j < 12; ++j) {
            float x = xp[j*64];
            acc[0][e] = fmaf(vm[(i0+0)*12 + j], x, acc[0][e]);
            acc[1][e] = fmaf(vm[(i0+1)*12 + j], x, acc[1][e]);
            acc[2][e] = fmaf(vm[(i0+2)*12 + j], x, acc[2][e]);
        }
    }
    #pragma unroll
    for (int i = 0; i < 3; ++i) {
        Bf8 v;
        #pragma unroll
        for (int e = 0; e < 8; ++e) v.e[e] = __float2bfloat16(acc[i][e]);
        *(bf16x8*)(Vt + (size_t)(b*NH + i0 + i)*(HD*TSEQ) + kb*2048 + dd*32 + g*8) = v.v;
    }
}

// ---------------- Kernel 3: attn8 (round-13/18/20 version VERBATIM) ----------
__global__ __launch_bounds__(256, 3) void attn8(
    const __hip_bfloat16* __restrict__ Qb,
    const __hip_bfloat16* __restrict__ Kt,
    const __hip_bfloat16* __restrict__ Vt,
    __hip_bfloat16* __restrict__ Y)
{
    __shared__ float Osh[4][2][64][20];   // [wave][half][lane][dt*4 +pad] = 40 KB
    __shared__ float Lsh[4][2][16];

    const int tid  = threadIdx.x;
    const int lane = tid & 63;
    const int w    = tid >> 6;      // 0..3
    const int lg   = lane >> 4;
    const int lc   = lane & 15;

    // XCD-aware bijective swizzle (768 = 8*96): 3 heads per XCD L2
    const int id  = blockIdx.x;
    const int id2 = (id & 7) * 96 + (id >> 3);
    const int bx  = id2 & 31;
    const int bh  = id2 >> 5;

    const float slope = c_slopes2[bh % NH];
    const __hip_bfloat16* Qp = Qb + (size_t)bh * TSEQ * HD;
    const __hip_bfloat16* Kp = Kt + (size_t)bh * 64 * 2048;
    const __hip_bfloat16* Vp = Vt + (size_t)bh * (HD * TSEQ);

    const float slgl  = slope * (float)(lg * 4);
    const float slp16 = slope * 16.0f;
    const int   s01   = lc + ((lg & 1) << 5);   // shfl sources (attn5-verified)
    const int   s23   = s01 + 16;
    const bool  hiK   = (lg >= 2);

    bf16x8 kA0, kA1, kA2, kA3, kB0, kB1, kB2, kB3;

#define LOADK(S, TI) do {                                                       \
    const __hip_bfloat16* kp_ = Kp + (size_t)(TI)*2048 + lane*8;                \
    k##S##0 = *(const bf16x8*)(kp_);                                            \
    k##S##1 = *(const bf16x8*)(kp_ + 512);                                      \
    k##S##2 = *(const bf16x8*)(kp_ + 1024);                                     \
    k##S##3 = *(const bf16x8*)(kp_ + 1536);                                     \
} while (0);

#define SHUF(P_, x0, x1, x2, x3)                                                \
    {                                                                           \
        int t00 = __shfl((int)x0, s01), t02 = __shfl((int)x2, s01);             \
        int t10 = __shfl((int)x1, s01), t12 = __shfl((int)x3, s01);             \
        int t20 = __shfl((int)x0, s23), t22 = __shfl((int)x2, s23);             \
        int t30 = __shfl((int)x1, s23), t32 = __shfl((int)x3, s23);             \
        P_.u[0] = hiK ? (unsigned)t02 : (unsigned)t00;                          \
        P_.u[1] = hiK ? (unsigned)t12 : (unsigned)t10;                          \
        P_.u[2] = hiK ? (unsigned)t22 : (unsigned)t20;                          \
        P_.u[3] = hiK ? (unsigned)t32 : (unsigned)t30;                          \
    }

#define CONS(TI, S) do {                                                        \
    const int K0C = (TI) * 32;                                                  \
    const __hip_bfloat16* vb_ = Vp + (size_t)(TI)*2048 + lc*32 + lg*8;          \
    bf16x8 v0_ = *(const bf16x8*)(vb_);                                         \
    bf16x8 v1_ = *(const bf16x8*)(vb_ + 512);                                   \
    bf16x8 v2_ = *(const bf16x8*)(vb_ + 1024);                                  \
    bf16x8 v3_ = *(const bf16x8*)(vb_ + 1536);                                  \
    f32x4 s0a = {}, s0b = {}, s1a = {}, s1b = {};                               \
    s0a = MFMA16(k##S##0, qfa0, s0a); s0a = MFMA16(k##S##1, qfa1, s0a);         \
    s0b = MFMA16(k##S##0, qfb0, s0b); s0b = MFMA16(k##S##1, qfb1, s0b);         \
    s1a = MFMA16(k##S##2, qfa0, s1a); s1a = MFMA16(k##S##3, qfa1, s1a);         \
    s1b = MFMA16(k##S##2, qfb0, s1b); s1b = MFMA16(k##S##3, qfb1, s1b);         \
    float base0_ = fmaf((float)K0C, slope, slgl);                               \
    float pa0[4], pa1[4], pb0[4], pb1[4];                                       \
    _Pragma("unroll")                                                           \
    for (int r = 0; r < 4; ++r) {                                               \
        float bk_  = base0_ + slope * (float)r;                                 \
        float bk1_ = bk_ + slp16;                                               \
        int kk0_ = K0C + lg*4 + r, kk1_ = kk0_ + 16;                            \
        float e0a = EXP2F(s0a[r] + (bk_  - eqa));                               \
        float e1a = EXP2F(s1a[r] + (bk1_ - eqa));                               \
        float e0b = EXP2F(s0b[r] + (bk_  - eqb));                               \
        float e1b = EXP2F(s1b[r] + (bk1_ - eqb));                               \
        pa0[r] = (kk0_ <= qia) ? e0a : 0.f;                                     \
        pa1[r] = (kk1_ <= qia) ? e1a : 0.f;                                     \
        pb0[r] = (kk0_ <= qib) ? e0b : 0.f;                                     \
        pb1[r] = (kk1_ <= qib) ? e1b : 0.f;                                     \
        lsa += pa0[r] + pa1[r];                                                 \
        lsb += pb0[r] + pb1[r];                                                 \
    }                                                                           \
    unsigned a0_ = pack2(pa0[0], pa0[1]), a1_ = pack2(pa0[2], pa0[3]);          \
    unsigned a2_ = pack2(pa1[0], pa1[1]), a3_ = pack2(pa1[2], pa1[3]);          \
    unsigned b0_ = pack2(pb0[0], pb0[1]), b1_ = pack2(pb0[2], pb0[3]);          \
    unsigned b2_ = pack2(pb1[0], pb1[1]), b3_ = pack2(pb1[2], pb1[3]);          \
    union { unsigned u[4]; bf16x8 v; } PA_, PB_;                                \
    SHUF(PA_, a0_, a1_, a2_, a3_)                                               \
    SHUF(PB_, b0_, b1_, b2_, b3_)                                               \
    Oa[0] = MFMA16(v0_, PA_.v, Oa[0]); Ob[0] = MFMA16(v0_, PB_.v, Ob[0]);       \
    Oa[1] = MFMA16(v1_, PA_.v, Oa[1]); Ob[1] = MFMA16(v1_, PB_.v, Ob[1]);       \
    Oa[2] = MFMA16(v2_, PA_.v, Oa[2]); Ob[2] = MFMA16(v2_, PB_.v, Ob[2]);       \
    Oa[3] = MFMA16(v3_, PA_.v, Oa[3]); Ob[3] = MFMA16(v3_, PB_.v, Ob[3]);       \
} while (0);

    auto runMember = [&](int qb, bool first) {
        const int q0m = qb * 32;
        const int qia = q0m + lc;
        const int qib = q0m + 16 + lc;
        const float eqa = slope * (float)qia + M2;
        const float eqb = slope * (float)qib + M2;

        bf16x8 qfa0 = *(const bf16x8*)(Qp + (size_t)qia * HD + lg*8);
        bf16x8 qfa1 = *(const bf16x8*)(Qp + (size_t)qia * HD + 32 + lg*8);
        bf16x8 qfb0 = *(const bf16x8*)(Qp + (size_t)qib * HD + lg*8);
        bf16x8 qfb1 = *(const bf16x8*)(Qp + (size_t)qib * HD + 32 + lg*8);

        f32x4 Oa[4] = {}; f32x4 Ob[4] = {};
        float lsa = 0.f, lsb = 0.f;

        // wave w handles member tiles w, w+4, ... (tiles of 32 keys; qb+1 total)
        const int myN = (qb >= w) ? ((qb - w) >> 2) + 1 : 0;

        if (myN > 0) {
            LOADK(A, w)
            int j = 0;
            while (true) {
                if (j + 1 < myN) LOADK(B, w + 4*(j+1))
                CONS(w + 4*j, A)
                ++j; if (j >= myN) break;
                if (j + 1 < myN) LOADK(A, w + 4*(j+1))
                CONS(w + 4*j, B)
                ++j; if (j >= myN) break;
            }
        }

        // reduce row-sums over the 4 lg lanes sharing lc
        lsa += __shfl_xor(lsa, 16); lsa += __shfl_xor(lsa, 32);
        lsb += __shfl_xor(lsb, 16); lsb += __shfl_xor(lsb, 32);

        // 4-way combine (partials add under fixed-max softmax)
        if (!first) __syncthreads();   // protect previous member's reads
        #pragma unroll
        for (int dt = 0; dt < 4; ++dt) {
            *(f32x4*)&Osh[w][0][lane][dt*4] = Oa[dt];
            *(f32x4*)&Osh[w][1][lane][dt*4] = Ob[dt];
        }
        if (lane < 16) {
            Lsh[w][0][lane] = lsa;
            Lsh[w][1][lane] = lsb;
        }
        __syncthreads();

        // wave w finalizes d-slice dt=w for both 16-row halves
        #pragma unroll
        for (int h = 0; h < 2; ++h) {
            f32x4 o = (h == 0) ? Oa[w] : Ob[w];
            #pragma unroll
            for (int w2 = 0; w2 < 4; ++w2)
                if (w2 != w) o += *(const f32x4*)&Osh[w2][h][lane][w*4];
            float lt = Lsh[0][h][lc] + Lsh[1][h][lc] + Lsh[2][h][lc] + Lsh[3][h][lc];
            float inv = 1.0f / lt;
            int q = q0m + h*16 + lc;
            ushort4 u;
            u.x = bf16bits(o[0] * inv);
            u.y = bf16bits(o[1] * inv);
            u.z = bf16bits(o[2] * inv);
            u.w = bf16bits(o[3] * inv);
            *(ushort4*)(Y + ((size_t)bh*TSEQ + q)*HD + w*16 + lg*4) = u;
        }
    };

    runMember(bx, true);        // light member
    runMember(63 - bx, false);  // heavy member (uniform 65 tiles per block)

#undef LOADK
#undef SHUF
#undef CONS
}

// ---------------- Kernel 4: out[b,t,i,d] = sum_j proj[i,j]*Y[b,j,t,d] ----------------
__global__ __launch_bounds__(256) void projmix(
    const __hip_bfloat16* __restrict__ Y, const float* __restrict__ ptmp,
    float* __restrict__ Out)
{
    __shared__ float pm[144];
    if (threadIdx.x < 144) pm[threadIdx.x] = ptmp[threadIdx.x];
    __syncthreads();
    int idx = blockIdx.x * 256 + threadIdx.x;
    int dd = idx & 63;
    int bt = idx >> 6;
    int t = bt & (TSEQ-1), b = bt >> 11;
    float yv[12];
    #pragma unroll
    for (int j = 0; j < 12; ++j)
        yv[j] = __bfloat162float(Y[(((size_t)(b*NH + j))*TSEQ + t)*HD + dd]);
    #pragma unroll
    for (int i = 0; i < 12; ++i) {
        float s = 0.f;
        #pragma unroll
        for (int j = 0; j < 12; ++j) s += pm[i*12+j] * yv[j];
        Out[(size_t)bt*CDIM + i*64 + dd] = s;
    }
}

extern "C" void kernel_launch(void* const* d_in, const int* in_sizes, int n_in,
                              void* d_out, int out_size, void* d_ws, size_t ws_size,
                              hipStream_t stream) {
    (void)in_sizes; (void)n_in; (void)out_size; (void)ws_size;
    const float* X    = (const float*)d_in[0];
    const float* XT   = (const float*)d_in[1];
    const float* W    = (const float*)d_in[2];
    const float* bias = (const float*)d_in[3];
    const float* vtmp = (const float*)d_in[4];
    const float* ptmp = (const float*)d_in[5];
    float* Out = (float*)d_out;

    char* ws = (char*)d_ws;
    const size_t BHTD = (size_t)2 * NH * TSEQ * HD;      // 3,145,728 elems
    __hip_bfloat16* Qb = (__hip_bfloat16*)ws;
    __hip_bfloat16* Kt = (__hip_bfloat16*)(ws + BHTD*2);   // fragment-interleaved K
    __hip_bfloat16* Vt = (__hip_bfloat16*)(ws + BHTD*4);   // interleaved V
    __hip_bfloat16* Yb = (__hip_bfloat16*)(ws + BHTD*6);

    gemm_qk<<<dim3(12, 32), 512, 0, stream>>>(X, W, bias, Qb, Kt);
    vmixt<<<512, 256, 0, stream>>>(XT, vtmp, Vt);
    attn8<<<768, 256, 0, stream>>>(Qb, Kt, Vt, Yb);
    projmix<<<1024, 256, 0, stream>>>(Yb, ptmp, Out);
}

// Round 22
// 78.774 us; speedup vs baseline: 1.0341x; 1.0341x over previous
//
#include <hip/hip_runtime.h>
#include <hip/hip_bf16.h>
#include <math.h>

// Problem constants: B=2, T=2048, C=768, H=12, hd=64
#define TSEQ 2048
#define CDIM 768
#define NH   12
#define HD   64

typedef __attribute__((ext_vector_type(8))) short bf16x8;   // 8 bf16 = 4 VGPRs (MFMA A/B frag)
typedef __attribute__((ext_vector_type(4))) float f32x4;    // MFMA C/D frag

union Bf8 { bf16x8 v; __hip_bfloat16 e[8]; };

// ALiBi slopes PRE-SCALED by 1/ln2 (softmax runs in exp2 domain)
__constant__ float c_slopes2[12] = {
    0.72134752f, 0.36067376f, 0.18033688f, 0.09016844f,
    0.04508422f, 0.02254211f, 0.011271055f, 0.0056355275f,
    1.02015692f, 0.72134752f, 0.51007846f, 0.36067376f
};
#define M2 4.3280851f          // 3/ln2  (fixed softmax max = 3, exp2 domain)
#define QSCALE 0.18033688f     // 0.125/ln2
#define EXP2F(x) __builtin_amdgcn_exp2f(x)

__device__ __forceinline__ unsigned pack2(float lo, float hi) {
    union { __hip_bfloat162 b; unsigned u; } cv;
    cv.b = __float22bfloat162_rn(make_float2(lo, hi));
    return cv.u;
}
__device__ __forceinline__ unsigned short bf16bits(float x) {
    union { __hip_bfloat16 b; unsigned short s; } cv;
    cv.b = __float2bfloat16(x);
    return cv.s;
}

#define MFMA16(a, b, c) __builtin_amdgcn_mfma_f32_16x16x32_bf16(a, b, c, 0, 0, 0)

// ---------------- Kernel 1: qk = x @ W^T + b  (M=4096,N=1536,K=768) ----------------
// 128x64 tile, 256 thr = 4 waves (2x2 of 64x32), grid (24,32) = 768 blocks.
// Q written natural (pre-scaled); K written in fragment-interleaved Kt2 layout.
__global__ __launch_bounds__(256) void gemm_qk(
    const float* __restrict__ X,
    const float* __restrict__ W,
    const float* __restrict__ bias,
    __hip_bfloat16* __restrict__ Qb,
    __hip_bfloat16* __restrict__ Kt)
{
    __shared__ alignas(16) __hip_bfloat16 As[128][40];
    __shared__ alignas(16) __hip_bfloat16 Bs[64][40];

    const int tid  = threadIdx.x;
    const int lane = tid & 63;
    const int w    = tid >> 6;       // 0..3
    const int lg   = lane >> 4;
    const int lc   = lane & 15;
    const int m0   = blockIdx.y * 128;
    const int n0   = blockIdx.x * 64;
    const int m0w  = (w >> 1) * 64;
    const int n0w  = (w & 1) * 32;

    const int r0 = tid >> 2;         // 0..63
    const int c0 = (tid & 3) * 8;    // 0,8,16,24

    f32x4 acc[4][2] = {};

    for (int k0 = 0; k0 < CDIM; k0 += 32) {
        __syncthreads();
        {
            const float* xp0 = X + (size_t)(m0 + r0) * CDIM + k0 + c0;
            const float* xp1 = X + (size_t)(m0 + r0 + 64) * CDIM + k0 + c0;
            const float* wp  = W + (size_t)(n0 + r0) * CDIM + k0 + c0;
            float4 a00 = *(const float4*)(xp0);
            float4 a01 = *(const float4*)(xp0 + 4);
            float4 a10 = *(const float4*)(xp1);
            float4 a11 = *(const float4*)(xp1 + 4);
            float4 b0  = *(const float4*)(wp);
            float4 b1  = *(const float4*)(wp + 4);
            Bf8 v0, v1, bv;
            v0.e[0]=__float2bfloat16(a00.x); v0.e[1]=__float2bfloat16(a00.y);
            v0.e[2]=__float2bfloat16(a00.z); v0.e[3]=__float2bfloat16(a00.w);
            v0.e[4]=__float2bfloat16(a01.x); v0.e[5]=__float2bfloat16(a01.y);
            v0.e[6]=__float2bfloat16(a01.z); v0.e[7]=__float2bfloat16(a01.w);
            v1.e[0]=__float2bfloat16(a10.x); v1.e[1]=__float2bfloat16(a10.y);
            v1.e[2]=__float2bfloat16(a10.z); v1.e[3]=__float2bfloat16(a10.w);
            v1.e[4]=__float2bfloat16(a11.x); v1.e[5]=__float2bfloat16(a11.y);
            v1.e[6]=__float2bfloat16(a11.z); v1.e[7]=__float2bfloat16(a11.w);
            bv.e[0]=__float2bfloat16(b0.x);  bv.e[1]=__float2bfloat16(b0.y);
            bv.e[2]=__float2bfloat16(b0.z);  bv.e[3]=__float2bfloat16(b0.w);
            bv.e[4]=__float2bfloat16(b1.x);  bv.e[5]=__float2bfloat16(b1.y);
            bv.e[6]=__float2bfloat16(b1.z);  bv.e[7]=__float2bfloat16(b1.w);
            *(bf16x8*)&As[r0][c0]      = v0.v;
            *(bf16x8*)&As[r0 + 64][c0] = v1.v;
            *(bf16x8*)&Bs[r0][c0]      = bv.v;
        }
        __syncthreads();

        bf16x8 af[4], bfr[2];
        #pragma unroll
        for (int mt = 0; mt < 4; ++mt)
            af[mt] = *(const bf16x8*)&As[m0w + mt*16 + lc][lg*8];
        #pragma unroll
        for (int nt = 0; nt < 2; ++nt)
            bfr[nt] = *(const bf16x8*)&Bs[n0w + nt*16 + lc][lg*8];
        #pragma unroll
        for (int mt = 0; mt < 4; ++mt)
            #pragma unroll
            for (int nt = 0; nt < 2; ++nt)
                acc[mt][nt] = MFMA16(af[mt], bfr[nt], acc[mt][nt]);
    }

    #pragma unroll
    for (int mt = 0; mt < 4; ++mt) {
        #pragma unroll
        for (int nt = 0; nt < 2; ++nt) {
            int n  = n0 + n0w + nt*16 + lc;
            float bv = bias[n];
            #pragma unroll
            for (int r = 0; r < 4; ++r) {
                int m = m0 + m0w + mt*16 + lg*4 + r;
                float v = acc[mt][nt][r] + bv;
                int b = m >> 11, t = m & (TSEQ-1);
                if (n < CDIM) {
                    int h = n >> 6, dd = n & 63;
                    Qb[(((size_t)(b*NH + h))*TSEQ + t)*HD + dd] = __float2bfloat16(v * QSCALE);
                } else {
                    int n2 = n - CDIM;
                    int h = n2 >> 6, dd = n2 & 63;
                    int bh_ = b*NH + h;
                    int kb = t >> 5, tt = t & 31;
                    int j  = ((tt >> 4) << 1) + (dd >> 5);
                    int ln = (((dd >> 3) & 3) << 4) + (tt & 15);
                    Kt[((size_t)(bh_*64 + kb))*2048 + j*512 + ln*8 + (dd & 7)] =
                        __float2bfloat16(v);
                }
            }
        }
    }
}

// ---------------- Kernel 2: vmixt — fused v head-mix + transpose -> Vt2 ----------------
// Block = (b, kb32, head-group of 3); wave g owns t-octet kb*32+g*8..+7; lane = d.
__global__ __launch_bounds__(256) void vmixt(
    const float* __restrict__ XT, const float* __restrict__ vtmp,
    __hip_bfloat16* __restrict__ Vt)
{
    __shared__ float vm[144];
    const int tid = threadIdx.x;
    if (tid < 144) vm[tid] = vtmp[tid];
    __syncthreads();

    // 512 blocks = 8 XCD chunks x 64: id2 consecutive within an XCD chunk
    const int id2 = (blockIdx.x & 7) * 64 + (blockIdx.x >> 3);
    const int ig  = id2 & 3;
    const int kbb = id2 >> 2;
    const int kb  = kbb & 63;
    const int b   = kbb >> 6;
    const int g   = tid >> 6;
    const int dd  = tid & 63;
    const int i0  = ig * 3;

    float acc[3][8];
    #pragma unroll
    for (int i = 0; i < 3; ++i)
        #pragma unroll
        for (int e = 0; e < 8; ++e) acc[i][e] = 0.f;

    const int tbase = kb*32 + g*8;
    #pragma unroll
    for (int e = 0; e < 8; ++e) {
        const float* xp = XT + ((size_t)(b*TSEQ + tbase + e))*CDIM + dd;
        #pragma unroll
        for (int j = 0; j < 12; ++j) {
            float x = xp[j*64];
            acc[0][e] = fmaf(vm[(i0+0)*12 + j], x, acc[0][e]);
            acc[1][e] = fmaf(vm[(i0+1)*12 + j], x, acc[1][e]);
            acc[2][e] = fmaf(vm[(i0+2)*12 + j], x, acc[2][e]);
        }
    }
    #pragma unroll
    for (int i = 0; i < 3; ++i) {
        Bf8 v;
        #pragma unroll
        for (int e = 0; e < 8; ++e) v.e[e] = __float2bfloat16(acc[i][e]);
        *(bf16x8*)(Vt + (size_t)(b*NH + i0 + i)*(HD*TSEQ) + kb*2048 + dd*32 + g*8) = v.v;
    }
}

// ---------------- Kernel 3: attn8 (round-13/18/20 version VERBATIM — proven optimum) ----
__global__ __launch_bounds__(256, 3) void attn8(
    const __hip_bfloat16* __restrict__ Qb,
    const __hip_bfloat16* __restrict__ Kt,
    const __hip_bfloat16* __restrict__ Vt,
    __hip_bfloat16* __restrict__ Y)
{
    __shared__ float Osh[4][2][64][20];   // [wave][half][lane][dt*4 +pad] = 40 KB
    __shared__ float Lsh[4][2][16];

    const int tid  = threadIdx.x;
    const int lane = tid & 63;
    const int w    = tid >> 6;      // 0..3
    const int lg   = lane >> 4;
    const int lc   = lane & 15;

    // XCD-aware bijective swizzle (768 = 8*96): 3 heads per XCD L2
    const int id  = blockIdx.x;
    const int id2 = (id & 7) * 96 + (id >> 3);
    const int bx  = id2 & 31;
    const int bh  = id2 >> 5;

    const float slope = c_slopes2[bh % NH];
    const __hip_bfloat16* Qp = Qb + (size_t)bh * TSEQ * HD;
    const __hip_bfloat16* Kp = Kt + (size_t)bh * 64 * 2048;
    const __hip_bfloat16* Vp = Vt + (size_t)bh * (HD * TSEQ);

    const float slgl  = slope * (float)(lg * 4);
    const float slp16 = slope * 16.0f;
    const int   s01   = lc + ((lg & 1) << 5);   // shfl sources (attn5-verified)
    const int   s23   = s01 + 16;
    const bool  hiK   = (lg >= 2);

    bf16x8 kA0, kA1, kA2, kA3, kB0, kB1, kB2, kB3;

#define LOADK(S, TI) do {                                                       \
    const __hip_bfloat16* kp_ = Kp + (size_t)(TI)*2048 + lane*8;                \
    k##S##0 = *(const bf16x8*)(kp_);                                            \
    k##S##1 = *(const bf16x8*)(kp_ + 512);                                      \
    k##S##2 = *(const bf16x8*)(kp_ + 1024);                                     \
    k##S##3 = *(const bf16x8*)(kp_ + 1536);                                     \
} while (0);

#define SHUF(P_, x0, x1, x2, x3)                                                \
    {                                                                           \
        int t00 = __shfl((int)x0, s01), t02 = __shfl((int)x2, s01);             \
        int t10 = __shfl((int)x1, s01), t12 = __shfl((int)x3, s01);             \
        int t20 = __shfl((int)x0, s23), t22 = __shfl((int)x2, s23);             \
        int t30 = __shfl((int)x1, s23), t32 = __shfl((int)x3, s23);             \
        P_.u[0] = hiK ? (unsigned)t02 : (unsigned)t00;                          \
        P_.u[1] = hiK ? (unsigned)t12 : (unsigned)t10;                          \
        P_.u[2] = hiK ? (unsigned)t22 : (unsigned)t20;                          \
        P_.u[3] = hiK ? (unsigned)t32 : (unsigned)t30;                          \
    }

#define CONS(TI, S) do {                                                        \
    const int K0C = (TI) * 32;                                                  \
    const __hip_bfloat16* vb_ = Vp + (size_t)(TI)*2048 + lc*32 + lg*8;          \
    bf16x8 v0_ = *(const bf16x8*)(vb_);                                         \
    bf16x8 v1_ = *(const bf16x8*)(vb_ + 512);                                   \
    bf16x8 v2_ = *(const bf16x8*)(vb_ + 1024);                                  \
    bf16x8 v3_ = *(const bf16x8*)(vb_ + 1536);                                  \
    f32x4 s0a = {}, s0b = {}, s1a = {}, s1b = {};                               \
    s0a = MFMA16(k##S##0, qfa0, s0a); s0a = MFMA16(k##S##1, qfa1, s0a);         \
    s0b = MFMA16(k##S##0, qfb0, s0b); s0b = MFMA16(k##S##1, qfb1, s0b);         \
    s1a = MFMA16(k##S##2, qfa0, s1a); s1a = MFMA16(k##S##3, qfa1, s1a);         \
    s1b = MFMA16(k##S##2, qfb0, s1b); s1b = MFMA16(k##S##3, qfb1, s1b);         \
    float base0_ = fmaf((float)K0C, slope, slgl);                               \
    float pa0[4], pa1[4], pb0[4], pb1[4];                                       \
    _Pragma("unroll")                                                           \
    for (int r = 0; r < 4; ++r) {                                               \
        float bk_  = base0_ + slope * (float)r;                                 \
        float bk1_ = bk_ + slp16;                                               \
        int kk0_ = K0C + lg*4 + r, kk1_ = kk0_ + 16;                            \
        float e0a = EXP2F(s0a[r] + (bk_  - eqa));                               \
        float e1a = EXP2F(s1a[r] + (bk1_ - eqa));                               \
        float e0b = EXP2F(s0b[r] + (bk_  - eqb));                               \
        float e1b = EXP2F(s1b[r] + (bk1_ - eqb));                               \
        pa0[r] = (kk0_ <= qia) ? e0a : 0.f;                                     \
        pa1[r] = (kk1_ <= qia) ? e1a : 0.f;                                     \
        pb0[r] = (kk0_ <= qib) ? e0b : 0.f;                                     \
        pb1[r] = (kk1_ <= qib) ? e1b : 0.f;                                     \
        lsa += pa0[r] + pa1[r];                                                 \
        lsb += pb0[r] + pb1[r];                                                 \
    }                                                                           \
    unsigned a0_ = pack2(pa0[0], pa0[1]), a1_ = pack2(pa0[2], pa0[3]);          \
    unsigned a2_ = pack2(pa1[0], pa1[1]), a3_ = pack2(pa1[2], pa1[3]);          \
    unsigned b0_ = pack2(pb0[0], pb0[1]), b1_ = pack2(pb0[2], pb0[3]);          \
    unsigned b2_ = pack2(pb1[0], pb1[1]), b3_ = pack2(pb1[2], pb1[3]);          \
    union { unsigned u[4]; bf16x8 v; } PA_, PB_;                                \
    SHUF(PA_, a0_, a1_, a2_, a3_)                                               \
    SHUF(PB_, b0_, b1_, b2_, b3_)                                               \
    Oa[0] = MFMA16(v0_, PA_.v, Oa[0]); Ob[0] = MFMA16(v0_, PB_.v, Ob[0]);       \
    Oa[1] = MFMA16(v1_, PA_.v, Oa[1]); Ob[1] = MFMA16(v1_, PB_.v, Ob[1]);       \
    Oa[2] = MFMA16(v2_, PA_.v, Oa[2]); Ob[2] = MFMA16(v2_, PB_.v, Ob[2]);       \
    Oa[3] = MFMA16(v3_, PA_.v, Oa[3]); Ob[3] = MFMA16(v3_, PB_.v, Ob[3]);       \
} while (0);

    auto runMember = [&](int qb, bool first) {
        const int q0m = qb * 32;
        const int qia = q0m + lc;
        const int qib = q0m + 16 + lc;
        const float eqa = slope * (float)qia + M2;
        const float eqb = slope * (float)qib + M2;

        bf16x8 qfa0 = *(const bf16x8*)(Qp + (size_t)qia * HD + lg*8);
        bf16x8 qfa1 = *(const bf16x8*)(Qp + (size_t)qia * HD + 32 + lg*8);
        bf16x8 qfb0 = *(const bf16x8*)(Qp + (size_t)qib * HD + lg*8);
        bf16x8 qfb1 = *(const bf16x8*)(Qp + (size_t)qib * HD + 32 + lg*8);

        f32x4 Oa[4] = {}; f32x4 Ob[4] = {};
        float lsa = 0.f, lsb = 0.f;

        // wave w handles member tiles w, w+4, ... (tiles of 32 keys; qb+1 total)
        const int myN = (qb >= w) ? ((qb - w) >> 2) + 1 : 0;

        if (myN > 0) {
            LOADK(A, w)
            int j = 0;
            while (true) {
                if (j + 1 < myN) LOADK(B, w + 4*(j+1))
                CONS(w + 4*j, A)
                ++j; if (j >= myN) break;
                if (j + 1 < myN) LOADK(A, w + 4*(j+1))
                CONS(w + 4*j, B)
                ++j; if (j >= myN) break;
            }
        }

        // reduce row-sums over the 4 lg lanes sharing lc
        lsa += __shfl_xor(lsa, 16); lsa += __shfl_xor(lsa, 32);
        lsb += __shfl_xor(lsb, 16); lsb += __shfl_xor(lsb, 32);

        // 4-way combine (partials add under fixed-max softmax)
        if (!first) __syncthreads();   // protect previous member's reads
        #pragma unroll
        for (int dt = 0; dt < 4; ++dt) {
            *(f32x4*)&Osh[w][0][lane][dt*4] = Oa[dt];
            *(f32x4*)&Osh[w][1][lane][dt*4] = Ob[dt];
        }
        if (lane < 16) {
            Lsh[w][0][lane] = lsa;
            Lsh[w][1][lane] = lsb;
        }
        __syncthreads();

        // wave w finalizes d-slice dt=w for both 16-row halves
        #pragma unroll
        for (int h = 0; h < 2; ++h) {
            f32x4 o = (h == 0) ? Oa[w] : Ob[w];
            #pragma unroll
            for (int w2 = 0; w2 < 4; ++w2)
                if (w2 != w) o += *(const f32x4*)&Osh[w2][h][lane][w*4];
            float lt = Lsh[0][h][lc] + Lsh[1][h][lc] + Lsh[2][h][lc] + Lsh[3][h][lc];
            float inv = 1.0f / lt;
            int q = q0m + h*16 + lc;
            ushort4 u;
            u.x = bf16bits(o[0] * inv);
            u.y = bf16bits(o[1] * inv);
            u.z = bf16bits(o[2] * inv);
            u.w = bf16bits(o[3] * inv);
            *(ushort4*)(Y + ((size_t)bh*TSEQ + q)*HD + w*16 + lg*4) = u;
        }
    };

    runMember(bx, true);        // light member
    runMember(63 - bx, false);  // heavy member (uniform 65 tiles per block)

#undef LOADK
#undef SHUF
#undef CONS
}

// ---------------- Kernel 4: out[b,t,i,d] = sum_j proj[i,j]*Y[b,j,t,d] ----------------
__global__ __launch_bounds__(256) void projmix(
    const __hip_bfloat16* __restrict__ Y, const float* __restrict__ ptmp,
    float* __restrict__ Out)
{
    __shared__ float pm[144];
    if (threadIdx.x < 144) pm[threadIdx.x] = ptmp[threadIdx.x];
    __syncthreads();
    int idx = blockIdx.x * 256 + threadIdx.x;
    int dd = idx & 63;
    int bt = idx >> 6;
    int t = bt & (TSEQ-1), b = bt >> 11;
    float yv[12];
    #pragma unroll
    for (int j = 0; j < 12; ++j)
        yv[j] = __bfloat162float(Y[(((size_t)(b*NH + j))*TSEQ + t)*HD + dd]);
    #pragma unroll
    for (int i = 0; i < 12; ++i) {
        float s = 0.f;
        #pragma unroll
        for (int j = 0; j < 12; ++j) s += pm[i*12+j] * yv[j];
        Out[(size_t)bt*CDIM + i*64 + dd] = s;
    }
}

extern "C" void kernel_launch(void* const* d_in, const int* in_sizes, int n_in,
                              void* d_out, int out_size, void* d_ws, size_t ws_size,
                              hipStream_t stream) {
    (void)in_sizes; (void)n_in; (void)out_size; (void)ws_size;
    const float* X    = (const float*)d_in[0];
    const float* XT   = (const float*)d_in[1];
    const float* W    = (const float*)d_in[2];
    const float* bias = (const float*)d_in[3];
    const float* vtmp = (const float*)d_in[4];
    const float* ptmp = (const float*)d_in[5];
    float* Out = (float*)d_out;

    char* ws = (char*)d_ws;
    const size_t BHTD = (size_t)2 * NH * TSEQ * HD;      // 3,145,728 elems
    __hip_bfloat16* Qb = (__hip_bfloat16*)ws;
    __hip_bfloat16* Kt = (__hip_bfloat16*)(ws + BHTD*2);   // fragment-interleaved K
    __hip_bfloat16* Vt = (__hip_bfloat16*)(ws + BHTD*4);   // interleaved V
    __hip_bfloat16* Yb = (__hip_bfloat16*)(ws + BHTD*6);

    gemm_qk<<<dim3(24, 32), 256, 0, stream>>>(X, W, bias, Qb, Kt);
    vmixt<<<512, 256, 0, stream>>>(XT, vtmp, Vt);
    attn8<<<768, 256, 0, stream>>>(Qb, Kt, Vt, Yb);
    projmix<<<1024, 256, 0, stream>>>(Yb, ptmp, Out);
}

// Round 23
// 77.668 us; speedup vs baseline: 1.0488x; 1.0142x over previous
//
#include <hip/hip_runtime.h>
#include <hip/hip_bf16.h>
#include <math.h>

// Problem constants: B=2, T=2048, C=768, H=12, hd=64
#define TSEQ 2048
#define CDIM 768
#define NH   12
#define HD   64

typedef __attribute__((ext_vector_type(8))) short bf16x8;   // 8 bf16 = 4 VGPRs (MFMA A/B frag)
typedef __attribute__((ext_vector_type(4))) float f32x4;    // MFMA C/D frag

union Bf8 { bf16x8 v; __hip_bfloat16 e[8]; };

// ALiBi slopes PRE-SCALED by 1/ln2 (softmax runs in exp2 domain)
__constant__ float c_slopes2[12] = {
    0.72134752f, 0.36067376f, 0.18033688f, 0.09016844f,
    0.04508422f, 0.02254211f, 0.011271055f, 0.0056355275f,
    1.02015692f, 0.72134752f, 0.51007846f, 0.36067376f
};
#define M2 4.3280851f          // 3/ln2  (fixed softmax max = 3, exp2 domain)
#define QSCALE 0.18033688f     // 0.125/ln2
#define EXP2F(x) __builtin_amdgcn_exp2f(x)

__device__ __forceinline__ unsigned pack2(float lo, float hi) {
    union { __hip_bfloat162 b; unsigned u; } cv;
    cv.b = __float22bfloat162_rn(make_float2(lo, hi));
    return cv.u;
}
__device__ __forceinline__ unsigned short bf16bits(float x) {
    union { __hip_bfloat16 b; unsigned short s; } cv;
    cv.b = __float2bfloat16(x);
    return cv.s;
}

#define MFMA16(a, b, c) __builtin_amdgcn_mfma_f32_16x16x32_bf16(a, b, c, 0, 0, 0)

// ---------------- Kernel 1: qk = x @ W^T + b  (M=4096,N=1536,K=768) ----------------
// 128x64 tile, 256 thr = 4 waves (2x2 of 64x32), grid (24,32) = 768 blocks.
// Q written natural (pre-scaled); K written in fragment-interleaved Kt2 layout.
__global__ __launch_bounds__(256) void gemm_qk(
    const float* __restrict__ X,
    const float* __restrict__ W,
    const float* __restrict__ bias,
    __hip_bfloat16* __restrict__ Qb,
    __hip_bfloat16* __restrict__ Kt)
{
    __shared__ alignas(16) __hip_bfloat16 As[128][40];
    __shared__ alignas(16) __hip_bfloat16 Bs[64][40];

    const int tid  = threadIdx.x;
    const int lane = tid & 63;
    const int w    = tid >> 6;       // 0..3
    const int lg   = lane >> 4;
    const int lc   = lane & 15;
    const int m0   = blockIdx.y * 128;
    const int n0   = blockIdx.x * 64;
    const int m0w  = (w >> 1) * 64;
    const int n0w  = (w & 1) * 32;

    const int r0 = tid >> 2;         // 0..63
    const int c0 = (tid & 3) * 8;    // 0,8,16,24

    f32x4 acc[4][2] = {};

    for (int k0 = 0; k0 < CDIM; k0 += 32) {
        __syncthreads();
        {
            const float* xp0 = X + (size_t)(m0 + r0) * CDIM + k0 + c0;
            const float* xp1 = X + (size_t)(m0 + r0 + 64) * CDIM + k0 + c0;
            const float* wp  = W + (size_t)(n0 + r0) * CDIM + k0 + c0;
            float4 a00 = *(const float4*)(xp0);
            float4 a01 = *(const float4*)(xp0 + 4);
            float4 a10 = *(const float4*)(xp1);
            float4 a11 = *(const float4*)(xp1 + 4);
            float4 b0  = *(const float4*)(wp);
            float4 b1  = *(const float4*)(wp + 4);
            Bf8 v0, v1, bv;
            v0.e[0]=__float2bfloat16(a00.x); v0.e[1]=__float2bfloat16(a00.y);
            v0.e[2]=__float2bfloat16(a00.z); v0.e[3]=__float2bfloat16(a00.w);
            v0.e[4]=__float2bfloat16(a01.x); v0.e[5]=__float2bfloat16(a01.y);
            v0.e[6]=__float2bfloat16(a01.z); v0.e[7]=__float2bfloat16(a01.w);
            v1.e[0]=__float2bfloat16(a10.x); v1.e[1]=__float2bfloat16(a10.y);
            v1.e[2]=__float2bfloat16(a10.z); v1.e[3]=__float2bfloat16(a10.w);
            v1.e[4]=__float2bfloat16(a11.x); v1.e[5]=__float2bfloat16(a11.y);
            v1.e[6]=__float2bfloat16(a11.z); v1.e[7]=__float2bfloat16(a11.w);
            bv.e[0]=__float2bfloat16(b0.x);  bv.e[1]=__float2bfloat16(b0.y);
            bv.e[2]=__float2bfloat16(b0.z);  bv.e[3]=__float2bfloat16(b0.w);
            bv.e[4]=__float2bfloat16(b1.x);  bv.e[5]=__float2bfloat16(b1.y);
            bv.e[6]=__float2bfloat16(b1.z);  bv.e[7]=__float2bfloat16(b1.w);
            *(bf16x8*)&As[r0][c0]      = v0.v;
            *(bf16x8*)&As[r0 + 64][c0] = v1.v;
            *(bf16x8*)&Bs[r0][c0]      = bv.v;
        }
        __syncthreads();

        bf16x8 af[4], bfr[2];
        #pragma unroll
        for (int mt = 0; mt < 4; ++mt)
            af[mt] = *(const bf16x8*)&As[m0w + mt*16 + lc][lg*8];
        #pragma unroll
        for (int nt = 0; nt < 2; ++nt)
            bfr[nt] = *(const bf16x8*)&Bs[n0w + nt*16 + lc][lg*8];
        #pragma unroll
        for (int mt = 0; mt < 4; ++mt)
            #pragma unroll
            for (int nt = 0; nt < 2; ++nt)
                acc[mt][nt] = MFMA16(af[mt], bfr[nt], acc[mt][nt]);
    }

    #pragma unroll
    for (int mt = 0; mt < 4; ++mt) {
        #pragma unroll
        for (int nt = 0; nt < 2; ++nt) {
            int n  = n0 + n0w + nt*16 + lc;
            float bv = bias[n];
            #pragma unroll
            for (int r = 0; r < 4; ++r) {
                int m = m0 + m0w + mt*16 + lg*4 + r;
                float v = acc[mt][nt][r] + bv;
                int b = m >> 11, t = m & (TSEQ-1);
                if (n < CDIM) {
                    int h = n >> 6, dd = n & 63;
                    Qb[(((size_t)(b*NH + h))*TSEQ + t)*HD + dd] = __float2bfloat16(v * QSCALE);
                } else {
                    int n2 = n - CDIM;
                    int h = n2 >> 6, dd = n2 & 63;
                    int bh_ = b*NH + h;
                    int kb = t >> 5, tt = t & 31;
                    int j  = ((tt >> 4) << 1) + (dd >> 5);
                    int ln = (((dd >> 3) & 3) << 4) + (tt & 15);
                    Kt[((size_t)(bh_*64 + kb))*2048 + j*512 + ln*8 + (dd & 7)] =
                        __float2bfloat16(v);
                }
            }
        }
    }
}

// ---------------- Kernel 2: vmixt — fused v head-mix + transpose -> Vt2 ----------------
// Block = (b, kb32, head-group of 3); wave g owns t-octet kb*32+g*8..+7; lane = d.
__global__ __launch_bounds__(256) void vmixt(
    const float* __restrict__ XT, const float* __restrict__ vtmp,
    __hip_bfloat16* __restrict__ Vt)
{
    __shared__ float vm[144];
    const int tid = threadIdx.x;
    if (tid < 144) vm[tid] = vtmp[tid];
    __syncthreads();

    // 512 blocks = 8 XCD chunks x 64: id2 consecutive within an XCD chunk
    const int id2 = (blockIdx.x & 7) * 64 + (blockIdx.x >> 3);
    const int ig  = id2 & 3;
    const int kbb = id2 >> 2;
    const int kb  = kbb & 63;
    const int b   = kbb >> 6;
    const int g   = tid >> 6;
    const int dd  = tid & 63;
    const int i0  = ig * 3;

    float acc[3][8];
    #pragma unroll
    for (int i = 0; i < 3; ++i)
        #pragma unroll
        for (int e = 0; e < 8; ++e) acc[i][e] = 0.f;

    const int tbase = kb*32 + g*8;
    #pragma unroll
    for (int e = 0; e < 8; ++e) {
        const float* xp = XT + ((size_t)(b*TSEQ + tbase + e))*CDIM + dd;
        #pragma unroll
        for (int j = 0; j < 12; ++j) {
            float x = xp[j*64];
            acc[0][e] = fmaf(vm[(i0+0)*12 + j], x, acc[0][e]);
            acc[1][e] = fmaf(vm[(i0+1)*12 + j], x, acc[1][e]);
            acc[2][e] = fmaf(vm[(i0+2)*12 + j], x, acc[2][e]);
        }
    }
    #pragma unroll
    for (int i = 0; i < 3; ++i) {
        Bf8 v;
        #pragma unroll
        for (int e = 0; e < 8; ++e) v.e[e] = __float2bfloat16(acc[i][e]);
        *(bf16x8*)(Vt + (size_t)(b*NH + i0 + i)*(HD*TSEQ) + kb*2048 + dd*32 + g*8) = v.v;
    }
}

// ---------------- Kernel 3: attn8p — round-20 attn8 + T5 s_setprio around MFMA ----------
// Waves in a block run barrier-free k-loops of DIFFERENT lengths (phase-diverse) —
// the measured-positive case for setprio (attn +4-7%, m191); zero VGPR impact.
__global__ __launch_bounds__(256, 3) void attn8p(
    const __hip_bfloat16* __restrict__ Qb,
    const __hip_bfloat16* __restrict__ Kt,
    const __hip_bfloat16* __restrict__ Vt,
    __hip_bfloat16* __restrict__ Y)
{
    __shared__ float Osh[4][2][64][20];   // [wave][half][lane][dt*4 +pad] = 40 KB
    __shared__ float Lsh[4][2][16];

    const int tid  = threadIdx.x;
    const int lane = tid & 63;
    const int w    = tid >> 6;      // 0..3
    const int lg   = lane >> 4;
    const int lc   = lane & 15;

    // XCD-aware bijective swizzle (768 = 8*96): 3 heads per XCD L2
    const int id  = blockIdx.x;
    const int id2 = (id & 7) * 96 + (id >> 3);
    const int bx  = id2 & 31;
    const int bh  = id2 >> 5;

    const float slope = c_slopes2[bh % NH];
    const __hip_bfloat16* Qp = Qb + (size_t)bh * TSEQ * HD;
    const __hip_bfloat16* Kp = Kt + (size_t)bh * 64 * 2048;
    const __hip_bfloat16* Vp = Vt + (size_t)bh * (HD * TSEQ);

    const float slgl  = slope * (float)(lg * 4);
    const float slp16 = slope * 16.0f;
    const int   s01   = lc + ((lg & 1) << 5);   // shfl sources (attn5-verified)
    const int   s23   = s01 + 16;
    const bool  hiK   = (lg >= 2);

    bf16x8 kA0, kA1, kA2, kA3, kB0, kB1, kB2, kB3;

#define LOADK(S, TI) do {                                                       \
    const __hip_bfloat16* kp_ = Kp + (size_t)(TI)*2048 + lane*8;                \
    k##S##0 = *(const bf16x8*)(kp_);                                            \
    k##S##1 = *(const bf16x8*)(kp_ + 512);                                      \
    k##S##2 = *(const bf16x8*)(kp_ + 1024);                                     \
    k##S##3 = *(const bf16x8*)(kp_ + 1536);                                     \
} while (0);

#define SHUF(P_, x0, x1, x2, x3)                                                \
    {                                                                           \
        int t00 = __shfl((int)x0, s01), t02 = __shfl((int)x2, s01);             \
        int t10 = __shfl((int)x1, s01), t12 = __shfl((int)x3, s01);             \
        int t20 = __shfl((int)x0, s23), t22 = __shfl((int)x2, s23);             \
        int t30 = __shfl((int)x1, s23), t32 = __shfl((int)x3, s23);             \
        P_.u[0] = hiK ? (unsigned)t02 : (unsigned)t00;                          \
        P_.u[1] = hiK ? (unsigned)t12 : (unsigned)t10;                          \
        P_.u[2] = hiK ? (unsigned)t22 : (unsigned)t20;                          \
        P_.u[3] = hiK ? (unsigned)t32 : (unsigned)t30;                          \
    }

#define CONS(TI, S) do {                                                        \
    const int K0C = (TI) * 32;                                                  \
    const __hip_bfloat16* vb_ = Vp + (size_t)(TI)*2048 + lc*32 + lg*8;          \
    bf16x8 v0_ = *(const bf16x8*)(vb_);                                         \
    bf16x8 v1_ = *(const bf16x8*)(vb_ + 512);                                   \
    bf16x8 v2_ = *(const bf16x8*)(vb_ + 1024);                                  \
    bf16x8 v3_ = *(const bf16x8*)(vb_ + 1536);                                  \
    f32x4 s0a = {}, s0b = {}, s1a = {}, s1b = {};                               \
    __builtin_amdgcn_s_setprio(1);                                              \
    s0a = MFMA16(k##S##0, qfa0, s0a); s0a = MFMA16(k##S##1, qfa1, s0a);         \
    s0b = MFMA16(k##S##0, qfb0, s0b); s0b = MFMA16(k##S##1, qfb1, s0b);         \
    s1a = MFMA16(k##S##2, qfa0, s1a); s1a = MFMA16(k##S##3, qfa1, s1a);         \
    s1b = MFMA16(k##S##2, qfb0, s1b); s1b = MFMA16(k##S##3, qfb1, s1b);         \
    __builtin_amdgcn_s_setprio(0);                                              \
    float base0_ = fmaf((float)K0C, slope, slgl);                               \
    float pa0[4], pa1[4], pb0[4], pb1[4];                                       \
    _Pragma("unroll")                                                           \
    for (int r = 0; r < 4; ++r) {                                               \
        float bk_  = base0_ + slope * (float)r;                                 \
        float bk1_ = bk_ + slp16;                                               \
        int kk0_ = K0C + lg*4 + r, kk1_ = kk0_ + 16;                            \
        float e0a = EXP2F(s0a[r] + (bk_  - eqa));                               \
        float e1a = EXP2F(s1a[r] + (bk1_ - eqa));                               \
        float e0b = EXP2F(s0b[r] + (bk_  - eqb));                               \
        float e1b = EXP2F(s1b[r] + (bk1_ - eqb));                               \
        pa0[r] = (kk0_ <= qia) ? e0a : 0.f;                                     \
        pa1[r] = (kk1_ <= qia) ? e1a : 0.f;                                     \
        pb0[r] = (kk0_ <= qib) ? e0b : 0.f;                                     \
        pb1[r] = (kk1_ <= qib) ? e1b : 0.f;                                     \
        lsa += pa0[r] + pa1[r];                                                 \
        lsb += pb0[r] + pb1[r];                                                 \
    }                                                                           \
    unsigned a0_ = pack2(pa0[0], pa0[1]), a1_ = pack2(pa0[2], pa0[3]);          \
    unsigned a2_ = pack2(pa1[0], pa1[1]), a3_ = pack2(pa1[2], pa1[3]);          \
    unsigned b0_ = pack2(pb0[0], pb0[1]), b1_ = pack2(pb0[2], pb0[3]);          \
    unsigned b2_ = pack2(pb1[0], pb1[1]), b3_ = pack2(pb1[2], pb1[3]);          \
    union { unsigned u[4]; bf16x8 v; } PA_, PB_;                                \
    SHUF(PA_, a0_, a1_, a2_, a3_)                                               \
    SHUF(PB_, b0_, b1_, b2_, b3_)                                               \
    __builtin_amdgcn_s_setprio(1);                                              \
    Oa[0] = MFMA16(v0_, PA_.v, Oa[0]); Ob[0] = MFMA16(v0_, PB_.v, Ob[0]);       \
    Oa[1] = MFMA16(v1_, PA_.v, Oa[1]); Ob[1] = MFMA16(v1_, PB_.v, Ob[1]);       \
    Oa[2] = MFMA16(v2_, PA_.v, Oa[2]); Ob[2] = MFMA16(v2_, PB_.v, Ob[2]);       \
    Oa[3] = MFMA16(v3_, PA_.v, Oa[3]); Ob[3] = MFMA16(v3_, PB_.v, Ob[3]);       \
    __builtin_amdgcn_s_setprio(0);                                              \
} while (0);

    auto runMember = [&](int qb, bool first) {
        const int q0m = qb * 32;
        const int qia = q0m + lc;
        const int qib = q0m + 16 + lc;
        const float eqa = slope * (float)qia + M2;
        const float eqb = slope * (float)qib + M2;

        bf16x8 qfa0 = *(const bf16x8*)(Qp + (size_t)qia * HD + lg*8);
        bf16x8 qfa1 = *(const bf16x8*)(Qp + (size_t)qia * HD + 32 + lg*8);
        bf16x8 qfb0 = *(const bf16x8*)(Qp + (size_t)qib * HD + lg*8);
        bf16x8 qfb1 = *(const bf16x8*)(Qp + (size_t)qib * HD + 32 + lg*8);

        f32x4 Oa[4] = {}; f32x4 Ob[4] = {};
        float lsa = 0.f, lsb = 0.f;

        // wave w handles member tiles w, w+4, ... (tiles of 32 keys; qb+1 total)
        const int myN = (qb >= w) ? ((qb - w) >> 2) + 1 : 0;

        if (myN > 0) {
            LOADK(A, w)
            int j = 0;
            while (true) {
                if (j + 1 < myN) LOADK(B, w + 4*(j+1))
                CONS(w + 4*j, A)
                ++j; if (j >= myN) break;
                if (j + 1 < myN) LOADK(A, w + 4*(j+1))
                CONS(w + 4*j, B)
                ++j; if (j >= myN) break;
            }
        }

        // reduce row-sums over the 4 lg lanes sharing lc
        lsa += __shfl_xor(lsa, 16); lsa += __shfl_xor(lsa, 32);
        lsb += __shfl_xor(lsb, 16); lsb += __shfl_xor(lsb, 32);

        // 4-way combine (partials add under fixed-max softmax)
        if (!first) __syncthreads();   // protect previous member's reads
        #pragma unroll
        for (int dt = 0; dt < 4; ++dt) {
            *(f32x4*)&Osh[w][0][lane][dt*4] = Oa[dt];
            *(f32x4*)&Osh[w][1][lane][dt*4] = Ob[dt];
        }
        if (lane < 16) {
            Lsh[w][0][lane] = lsa;
            Lsh[w][1][lane] = lsb;
        }
        __syncthreads();

        // wave w finalizes d-slice dt=w for both 16-row halves
        #pragma unroll
        for (int h = 0; h < 2; ++h) {
            f32x4 o = (h == 0) ? Oa[w] : Ob[w];
            #pragma unroll
            for (int w2 = 0; w2 < 4; ++w2)
                if (w2 != w) o += *(const f32x4*)&Osh[w2][h][lane][w*4];
            float lt = Lsh[0][h][lc] + Lsh[1][h][lc] + Lsh[2][h][lc] + Lsh[3][h][lc];
            float inv = 1.0f / lt;
            int q = q0m + h*16 + lc;
            ushort4 u;
            u.x = bf16bits(o[0] * inv);
            u.y = bf16bits(o[1] * inv);
            u.z = bf16bits(o[2] * inv);
            u.w = bf16bits(o[3] * inv);
            *(ushort4*)(Y + ((size_t)bh*TSEQ + q)*HD + w*16 + lg*4) = u;
        }
    };

    runMember(bx, true);        // light member
    runMember(63 - bx, false);  // heavy member (uniform 65 tiles per block)

#undef LOADK
#undef SHUF
#undef CONS
}

// ---------------- Kernel 4: out[b,t,i,d] = sum_j proj[i,j]*Y[b,j,t,d] ----------------
__global__ __launch_bounds__(256) void projmix(
    const __hip_bfloat16* __restrict__ Y, const float* __restrict__ ptmp,
    float* __restrict__ Out)
{
    __shared__ float pm[144];
    if (threadIdx.x < 144) pm[threadIdx.x] = ptmp[threadIdx.x];
    __syncthreads();
    int idx = blockIdx.x * 256 + threadIdx.x;
    int dd = idx & 63;
    int bt = idx >> 6;
    int t = bt & (TSEQ-1), b = bt >> 11;
    float yv[12];
    #pragma unroll
    for (int j = 0; j < 12; ++j)
        yv[j] = __bfloat162float(Y[(((size_t)(b*NH + j))*TSEQ + t)*HD + dd]);
    #pragma unroll
    for (int i = 0; i < 12; ++i) {
        float s = 0.f;
        #pragma unroll
        for (int j = 0; j < 12; ++j) s += pm[i*12+j] * yv[j];
        Out[(size_t)bt*CDIM + i*64 + dd] = s;
    }
}

extern "C" void kernel_launch(void* const* d_in, const int* in_sizes, int n_in,
                              void* d_out, int out_size, void* d_ws, size_t ws_size,
                              hipStream_t stream) {
    (void)in_sizes; (void)n_in; (void)out_size; (void)ws_size;
    const float* X    = (const float*)d_in[0];
    const float* XT   = (const float*)d_in[1];
    const float* W    = (const float*)d_in[2];
    const float* bias = (const float*)d_in[3];
    const float* vtmp = (const float*)d_in[4];
    const float* ptmp = (const float*)d_in[5];
    float* Out = (float*)d_out;

    char* ws = (char*)d_ws;
    const size_t BHTD = (size_t)2 * NH * TSEQ * HD;      // 3,145,728 elems
    __hip_bfloat16* Qb = (__hip_bfloat16*)ws;
    __hip_bfloat16* Kt = (__hip_bfloat16*)(ws + BHTD*2);   // fragment-interleaved K
    __hip_bfloat16* Vt = (__hip_bfloat16*)(ws + BHTD*4);   // interleaved V
    __hip_bfloat16* Yb = (__hip_bfloat16*)(ws + BHTD*6);

    gemm_qk<<<dim3(24, 32), 256, 0, stream>>>(X, W, bias, Qb, Kt);
    vmixt<<<512, 256, 0, stream>>>(XT, vtmp, Vt);
    attn8p<<<768, 256, 0, stream>>>(Qb, Kt, Vt, Yb);
    projmix<<<1024, 256, 0, stream>>>(Yb, ptmp, Out);
}

// Round 24
// 77.650 us; speedup vs baseline: 1.0491x; 1.0002x over previous
//
#include <hip/hip_runtime.h>
#include <hip/hip_bf16.h>
#include <math.h>

// Problem constants: B=2, T=2048, C=768, H=12, hd=64
#define TSEQ 2048
#define CDIM 768
#define NH   12
#define HD   64

typedef __attribute__((ext_vector_type(8))) short bf16x8;   // 8 bf16 = 4 VGPRs (MFMA A/B frag)
typedef __attribute__((ext_vector_type(4))) float f32x4;    // MFMA C/D frag

union Bf8 { bf16x8 v; __hip_bfloat16 e[8]; };

// ALiBi slopes PRE-SCALED by 1/ln2 (softmax runs in exp2 domain)
__constant__ float c_slopes2[12] = {
    0.72134752f, 0.36067376f, 0.18033688f, 0.09016844f,
    0.04508422f, 0.02254211f, 0.011271055f, 0.0056355275f,
    1.02015692f, 0.72134752f, 0.51007846f, 0.36067376f
};
#define M2 4.3280851f          // 3/ln2  (fixed softmax max = 3, exp2 domain)
#define QSCALE 0.18033688f     // 0.125/ln2
#define EXP2F(x) __builtin_amdgcn_exp2f(x)

__device__ __forceinline__ unsigned pack2(float lo, float hi) {
    union { __hip_bfloat162 b; unsigned u; } cv;
    cv.b = __float22bfloat162_rn(make_float2(lo, hi));
    return cv.u;
}
__device__ __forceinline__ unsigned short bf16bits(float x) {
    union { __hip_bfloat16 b; unsigned short s; } cv;
    cv.b = __float2bfloat16(x);
    return cv.s;
}

#define MFMA16(a, b, c) __builtin_amdgcn_mfma_f32_16x16x32_bf16(a, b, c, 0, 0, 0)

// ---------------- Kernel 1: qk = x @ W^T + b  (M=4096,N=1536,K=768) ----------------
// 128x64 tile, 256 thr = 4 waves (2x2 of 64x32), grid (24,32) = 768 blocks.
// Q written natural (pre-scaled); K written in fragment-interleaved Kt2 layout.
__global__ __launch_bounds__(256) void gemm_qk(
    const float* __restrict__ X,
    const float* __restrict__ W,
    const float* __restrict__ bias,
    __hip_bfloat16* __restrict__ Qb,
    __hip_bfloat16* __restrict__ Kt)
{
    __shared__ alignas(16) __hip_bfloat16 As[128][40];
    __shared__ alignas(16) __hip_bfloat16 Bs[64][40];

    const int tid  = threadIdx.x;
    const int lane = tid & 63;
    const int w    = tid >> 6;       // 0..3
    const int lg   = lane >> 4;
    const int lc   = lane & 15;
    const int m0   = blockIdx.y * 128;
    const int n0   = blockIdx.x * 64;
    const int m0w  = (w >> 1) * 64;
    const int n0w  = (w & 1) * 32;

    const int r0 = tid >> 2;         // 0..63
    const int c0 = (tid & 3) * 8;    // 0,8,16,24

    f32x4 acc[4][2] = {};

    for (int k0 = 0; k0 < CDIM; k0 += 32) {
        __syncthreads();
        {
            const float* xp0 = X + (size_t)(m0 + r0) * CDIM + k0 + c0;
            const float* xp1 = X + (size_t)(m0 + r0 + 64) * CDIM + k0 + c0;
            const float* wp  = W + (size_t)(n0 + r0) * CDIM + k0 + c0;
            float4 a00 = *(const float4*)(xp0);
            float4 a01 = *(const float4*)(xp0 + 4);
            float4 a10 = *(const float4*)(xp1);
            float4 a11 = *(const float4*)(xp1 + 4);
            float4 b0  = *(const float4*)(wp);
            float4 b1  = *(const float4*)(wp + 4);
            Bf8 v0, v1, bv;
            v0.e[0]=__float2bfloat16(a00.x); v0.e[1]=__float2bfloat16(a00.y);
            v0.e[2]=__float2bfloat16(a00.z); v0.e[3]=__float2bfloat16(a00.w);
            v0.e[4]=__float2bfloat16(a01.x); v0.e[5]=__float2bfloat16(a01.y);
            v0.e[6]=__float2bfloat16(a01.z); v0.e[7]=__float2bfloat16(a01.w);
            v1.e[0]=__float2bfloat16(a10.x); v1.e[1]=__float2bfloat16(a10.y);
            v1.e[2]=__float2bfloat16(a10.z); v1.e[3]=__float2bfloat16(a10.w);
            v1.e[4]=__float2bfloat16(a11.x); v1.e[5]=__float2bfloat16(a11.y);
            v1.e[6]=__float2bfloat16(a11.z); v1.e[7]=__float2bfloat16(a11.w);
            bv.e[0]=__float2bfloat16(b0.x);  bv.e[1]=__float2bfloat16(b0.y);
            bv.e[2]=__float2bfloat16(b0.z);  bv.e[3]=__float2bfloat16(b0.w);
            bv.e[4]=__float2bfloat16(b1.x);  bv.e[5]=__float2bfloat16(b1.y);
            bv.e[6]=__float2bfloat16(b1.z);  bv.e[7]=__float2bfloat16(b1.w);
            *(bf16x8*)&As[r0][c0]      = v0.v;
            *(bf16x8*)&As[r0 + 64][c0] = v1.v;
            *(bf16x8*)&Bs[r0][c0]      = bv.v;
        }
        __syncthreads();

        bf16x8 af[4], bfr[2];
        #pragma unroll
        for (int mt = 0; mt < 4; ++mt)
            af[mt] = *(const bf16x8*)&As[m0w + mt*16 + lc][lg*8];
        #pragma unroll
        for (int nt = 0; nt < 2; ++nt)
            bfr[nt] = *(const bf16x8*)&Bs[n0w + nt*16 + lc][lg*8];
        #pragma unroll
        for (int mt = 0; mt < 4; ++mt)
            #pragma unroll
            for (int nt = 0; nt < 2; ++nt)
                acc[mt][nt] = MFMA16(af[mt], bfr[nt], acc[mt][nt]);
    }

    #pragma unroll
    for (int mt = 0; mt < 4; ++mt) {
        #pragma unroll
        for (int nt = 0; nt < 2; ++nt) {
            int n  = n0 + n0w + nt*16 + lc;
            float bv = bias[n];
            #pragma unroll
            for (int r = 0; r < 4; ++r) {
                int m = m0 + m0w + mt*16 + lg*4 + r;
                float v = acc[mt][nt][r] + bv;
                int b = m >> 11, t = m & (TSEQ-1);
                if (n < CDIM) {
                    int h = n >> 6, dd = n & 63;
                    Qb[(((size_t)(b*NH + h))*TSEQ + t)*HD + dd] = __float2bfloat16(v * QSCALE);
                } else {
                    int n2 = n - CDIM;
                    int h = n2 >> 6, dd = n2 & 63;
                    int bh_ = b*NH + h;
                    int kb = t >> 5, tt = t & 31;
                    int j  = ((tt >> 4) << 1) + (dd >> 5);
                    int ln = (((dd >> 3) & 3) << 4) + (tt & 15);
                    Kt[((size_t)(bh_*64 + kb))*2048 + j*512 + ln*8 + (dd & 7)] =
                        __float2bfloat16(v);
                }
            }
        }
    }
}

// ---------------- Kernel 2: vmixt — fused v head-mix + transpose -> Vt2 ----------------
// Block = (b, kb32, head-group of 3); wave g owns t-octet kb*32+g*8..+7; lane = d.
__global__ __launch_bounds__(256) void vmixt(
    const float* __restrict__ XT, const float* __restrict__ vtmp,
    __hip_bfloat16* __restrict__ Vt)
{
    __shared__ float vm[144];
    const int tid = threadIdx.x;
    if (tid < 144) vm[tid] = vtmp[tid];
    __syncthreads();

    // 512 blocks = 8 XCD chunks x 64: id2 consecutive within an XCD chunk
    const int id2 = (blockIdx.x & 7) * 64 + (blockIdx.x >> 3);
    const int ig  = id2 & 3;
    const int kbb = id2 >> 2;
    const int kb  = kbb & 63;
    const int b   = kbb >> 6;
    const int g   = tid >> 6;
    const int dd  = tid & 63;
    const int i0  = ig * 3;

    float acc[3][8];
    #pragma unroll
    for (int i = 0; i < 3; ++i)
        #pragma unroll
        for (int e = 0; e < 8; ++e) acc[i][e] = 0.f;

    const int tbase = kb*32 + g*8;
    #pragma unroll
    for (int e = 0; e < 8; ++e) {
        const float* xp = XT + ((size_t)(b*TSEQ + tbase + e))*CDIM + dd;
        #pragma unroll
        for (int j = 0; j < 12; ++j) {
            float x = xp[j*64];
            acc[0][e] = fmaf(vm[(i0+0)*12 + j], x, acc[0][e]);
            acc[1][e] = fmaf(vm[(i0+1)*12 + j], x, acc[1][e]);
            acc[2][e] = fmaf(vm[(i0+2)*12 + j], x, acc[2][e]);
        }
    }
    #pragma unroll
    for (int i = 0; i < 3; ++i) {
        Bf8 v;
        #pragma unroll
        for (int e = 0; e < 8; ++e) v.e[e] = __float2bfloat16(acc[i][e]);
        *(bf16x8*)(Vt + (size_t)(b*NH + i0 + i)*(HD*TSEQ) + kb*2048 + dd*32 + g*8) = v.v;
    }
}

// ---------------- Kernel 3: attn8p — attn8 + T5 s_setprio around MFMA clusters ----------
// Champion config (round 23: 77.7us). Waves run barrier-free k-loops of different
// lengths (phase-diverse) — the measured-positive setprio case; zero VGPR impact.
__global__ __launch_bounds__(256, 3) void attn8p(
    const __hip_bfloat16* __restrict__ Qb,
    const __hip_bfloat16* __restrict__ Kt,
    const __hip_bfloat16* __restrict__ Vt,
    __hip_bfloat16* __restrict__ Y)
{
    __shared__ float Osh[4][2][64][20];   // [wave][half][lane][dt*4 +pad] = 40 KB
    __shared__ float Lsh[4][2][16];

    const int tid  = threadIdx.x;
    const int lane = tid & 63;
    const int w    = tid >> 6;      // 0..3
    const int lg   = lane >> 4;
    const int lc   = lane & 15;

    // XCD-aware bijective swizzle (768 = 8*96): 3 heads per XCD L2
    const int id  = blockIdx.x;
    const int id2 = (id & 7) * 96 + (id >> 3);
    const int bx  = id2 & 31;
    const int bh  = id2 >> 5;

    const float slope = c_slopes2[bh % NH];
    const __hip_bfloat16* Qp = Qb + (size_t)bh * TSEQ * HD;
    const __hip_bfloat16* Kp = Kt + (size_t)bh * 64 * 2048;
    const __hip_bfloat16* Vp = Vt + (size_t)bh * (HD * TSEQ);

    const float slgl  = slope * (float)(lg * 4);
    const float slp16 = slope * 16.0f;
    const int   s01   = lc + ((lg & 1) << 5);   // shfl sources (attn5-verified)
    const int   s23   = s01 + 16;
    const bool  hiK   = (lg >= 2);

    bf16x8 kA0, kA1, kA2, kA3, kB0, kB1, kB2, kB3;

#define LOADK(S, TI) do {                                                       \
    const __hip_bfloat16* kp_ = Kp + (size_t)(TI)*2048 + lane*8;                \
    k##S##0 = *(const bf16x8*)(kp_);                                            \
    k##S##1 = *(const bf16x8*)(kp_ + 512);                                      \
    k##S##2 = *(const bf16x8*)(kp_ + 1024);                                     \
    k##S##3 = *(const bf16x8*)(kp_ + 1536);                                     \
} while (0);

#define SHUF(P_, x0, x1, x2, x3)                                                \
    {                                                                           \
        int t00 = __shfl((int)x0, s01), t02 = __shfl((int)x2, s01);             \
        int t10 = __shfl((int)x1, s01), t12 = __shfl((int)x3, s01);             \
        int t20 = __shfl((int)x0, s23), t22 = __shfl((int)x2, s23);             \
        int t30 = __shfl((int)x1, s23), t32 = __shfl((int)x3, s23);             \
        P_.u[0] = hiK ? (unsigned)t02 : (unsigned)t00;                          \
        P_.u[1] = hiK ? (unsigned)t12 : (unsigned)t10;                          \
        P_.u[2] = hiK ? (unsigned)t22 : (unsigned)t20;                          \
        P_.u[3] = hiK ? (unsigned)t32 : (unsigned)t30;                          \
    }

#define CONS(TI, S) do {                                                        \
    const int K0C = (TI) * 32;                                                  \
    const __hip_bfloat16* vb_ = Vp + (size_t)(TI)*2048 + lc*32 + lg*8;          \
    bf16x8 v0_ = *(const bf16x8*)(vb_);                                         \
    bf16x8 v1_ = *(const bf16x8*)(vb_ + 512);                                   \
    bf16x8 v2_ = *(const bf16x8*)(vb_ + 1024);                                  \
    bf16x8 v3_ = *(const bf16x8*)(vb_ + 1536);                                  \
    f32x4 s0a = {}, s0b = {}, s1a = {}, s1b = {};                               \
    __builtin_amdgcn_s_setprio(1);                                              \
    s0a = MFMA16(k##S##0, qfa0, s0a); s0a = MFMA16(k##S##1, qfa1, s0a);         \
    s0b = MFMA16(k##S##0, qfb0, s0b); s0b = MFMA16(k##S##1, qfb1, s0b);         \
    s1a = MFMA16(k##S##2, qfa0, s1a); s1a = MFMA16(k##S##3, qfa1, s1a);         \
    s1b = MFMA16(k##S##2, qfb0, s1b); s1b = MFMA16(k##S##3, qfb1, s1b);         \
    __builtin_amdgcn_s_setprio(0);                                              \
    float base0_ = fmaf((float)K0C, slope, slgl);                               \
    float pa0[4], pa1[4], pb0[4], pb1[4];                                       \
    _Pragma("unroll")                                                           \
    for (int r = 0; r < 4; ++r) {                                               \
        float bk_  = base0_ + slope * (float)r;                                 \
        float bk1_ = bk_ + slp16;                                               \
        int kk0_ = K0C + lg*4 + r, kk1_ = kk0_ + 16;                            \
        float e0a = EXP2F(s0a[r] + (bk_  - eqa));                               \
        float e1a = EXP2F(s1a[r] + (bk1_ - eqa));                               \
        float e0b = EXP2F(s0b[r] + (bk_  - eqb));                               \
        float e1b = EXP2F(s1b[r] + (bk1_ - eqb));                               \
        pa0[r] = (kk0_ <= qia) ? e0a : 0.f;                                     \
        pa1[r] = (kk1_ <= qia) ? e1a : 0.f;                                     \
        pb0[r] = (kk0_ <= qib) ? e0b : 0.f;                                     \
        pb1[r] = (kk1_ <= qib) ? e1b : 0.f;                                     \
        lsa += pa0[r] + pa1[r];                                                 \
        lsb += pb0[r] + pb1[r];                                                 \
    }                                                                           \
    unsigned a0_ = pack2(pa0[0], pa0[1]), a1_ = pack2(pa0[2], pa0[3]);          \
    unsigned a2_ = pack2(pa1[0], pa1[1]), a3_ = pack2(pa1[2], pa1[3]);          \
    unsigned b0_ = pack2(pb0[0], pb0[1]), b1_ = pack2(pb0[2], pb0[3]);          \
    unsigned b2_ = pack2(pb1[0], pb1[1]), b3_ = pack2(pb1[2], pb1[3]);          \
    union { unsigned u[4]; bf16x8 v; } PA_, PB_;                                \
    SHUF(PA_, a0_, a1_, a2_, a3_)                                               \
    SHUF(PB_, b0_, b1_, b2_, b3_)                                               \
    __builtin_amdgcn_s_setprio(1);                                              \
    Oa[0] = MFMA16(v0_, PA_.v, Oa[0]); Ob[0] = MFMA16(v0_, PB_.v, Ob[0]);       \
    Oa[1] = MFMA16(v1_, PA_.v, Oa[1]); Ob[1] = MFMA16(v1_, PB_.v, Ob[1]);       \
    Oa[2] = MFMA16(v2_, PA_.v, Oa[2]); Ob[2] = MFMA16(v2_, PB_.v, Ob[2]);       \
    Oa[3] = MFMA16(v3_, PA_.v, Oa[3]); Ob[3] = MFMA16(v3_, PB_.v, Ob[3]);       \
    __builtin_amdgcn_s_setprio(0);                                              \
} while (0);

    auto runMember = [&](int qb, bool first) {
        const int q0m = qb * 32;
        const int qia = q0m + lc;
        const int qib = q0m + 16 + lc;
        const float eqa = slope * (float)qia + M2;
        const float eqb = slope * (float)qib + M2;

        bf16x8 qfa0 = *(const bf16x8*)(Qp + (size_t)qia * HD + lg*8);
        bf16x8 qfa1 = *(const bf16x8*)(Qp + (size_t)qia * HD + 32 + lg*8);
        bf16x8 qfb0 = *(const bf16x8*)(Qp + (size_t)qib * HD + lg*8);
        bf16x8 qfb1 = *(const bf16x8*)(Qp + (size_t)qib * HD + 32 + lg*8);

        f32x4 Oa[4] = {}; f32x4 Ob[4] = {};
        float lsa = 0.f, lsb = 0.f;

        // wave w handles member tiles w, w+4, ... (tiles of 32 keys; qb+1 total)
        const int myN = (qb >= w) ? ((qb - w) >> 2) + 1 : 0;

        if (myN > 0) {
            LOADK(A, w)
            int j = 0;
            while (true) {
                if (j + 1 < myN) LOADK(B, w + 4*(j+1))
                CONS(w + 4*j, A)
                ++j; if (j >= myN) break;
                if (j + 1 < myN) LOADK(A, w + 4*(j+1))
                CONS(w + 4*j, B)
                ++j; if (j >= myN) break;
            }
        }

        // reduce row-sums over the 4 lg lanes sharing lc
        lsa += __shfl_xor(lsa, 16); lsa += __shfl_xor(lsa, 32);
        lsb += __shfl_xor(lsb, 16); lsb += __shfl_xor(lsb, 32);

        // 4-way combine (partials add under fixed-max softmax)
        if (!first) __syncthreads();   // protect previous member's reads
        #pragma unroll
        for (int dt = 0; dt < 4; ++dt) {
            *(f32x4*)&Osh[w][0][lane][dt*4] = Oa[dt];
            *(f32x4*)&Osh[w][1][lane][dt*4] = Ob[dt];
        }
        if (lane < 16) {
            Lsh[w][0][lane] = lsa;
            Lsh[w][1][lane] = lsb;
        }
        __syncthreads();

        // wave w finalizes d-slice dt=w for both 16-row halves
        #pragma unroll
        for (int h = 0; h < 2; ++h) {
            f32x4 o = (h == 0) ? Oa[w] : Ob[w];
            #pragma unroll
            for (int w2 = 0; w2 < 4; ++w2)
                if (w2 != w) o += *(const f32x4*)&Osh[w2][h][lane][w*4];
            float lt = Lsh[0][h][lc] + Lsh[1][h][lc] + Lsh[2][h][lc] + Lsh[3][h][lc];
            float inv = 1.0f / lt;
            int q = q0m + h*16 + lc;
            ushort4 u;
            u.x = bf16bits(o[0] * inv);
            u.y = bf16bits(o[1] * inv);
            u.z = bf16bits(o[2] * inv);
            u.w = bf16bits(o[3] * inv);
            *(ushort4*)(Y + ((size_t)bh*TSEQ + q)*HD + w*16 + lg*4) = u;
        }
    };

    runMember(bx, true);        // light member
    runMember(63 - bx, false);  // heavy member (uniform 65 tiles per block)

#undef LOADK
#undef SHUF
#undef CONS
}

// ---------------- Kernel 4: out[b,t,i,d] = sum_j proj[i,j]*Y[b,j,t,d] ----------------
__global__ __launch_bounds__(256) void projmix(
    const __hip_bfloat16* __restrict__ Y, const float* __restrict__ ptmp,
    float* __restrict__ Out)
{
    __shared__ float pm[144];
    if (threadIdx.x < 144) pm[threadIdx.x] = ptmp[threadIdx.x];
    __syncthreads();
    int idx = blockIdx.x * 256 + threadIdx.x;
    int dd = idx & 63;
    int bt = idx >> 6;
    int t = bt & (TSEQ-1), b = bt >> 11;
    float yv[12];
    #pragma unroll
    for (int j = 0; j < 12; ++j)
        yv[j] = __bfloat162float(Y[(((size_t)(b*NH + j))*TSEQ + t)*HD + dd]);
    #pragma unroll
    for (int i = 0; i < 12; ++i) {
        float s = 0.f;
        #pragma unroll
        for (int j = 0; j < 12; ++j) s += pm[i*12+j] * yv[j];
        Out[(size_t)bt*CDIM + i*64 + dd] = s;
    }
}

extern "C" void kernel_launch(void* const* d_in, const int* in_sizes, int n_in,
                              void* d_out, int out_size, void* d_ws, size_t ws_size,
                              hipStream_t stream) {
    (void)in_sizes; (void)n_in; (void)out_size; (void)ws_size;
    const float* X    = (const float*)d_in[0];
    const float* XT   = (const float*)d_in[1];
    const float* W    = (const float*)d_in[2];
    const float* bias = (const float*)d_in[3];
    const float* vtmp = (const float*)d_in[4];
    const float* ptmp = (const float*)d_in[5];
    float* Out = (float*)d_out;

    char* ws = (char*)d_ws;
    const size_t BHTD = (size_t)2 * NH * TSEQ * HD;      // 3,145,728 elems
    __hip_bfloat16* Qb = (__hip_bfloat16*)ws;
    __hip_bfloat16* Kt = (__hip_bfloat16*)(ws + BHTD*2);   // fragment-interleaved K
    __hip_bfloat16* Vt = (__hip_bfloat16*)(ws + BHTD*4);   // interleaved V
    __hip_bfloat16* Yb = (__hip_bfloat16*)(ws + BHTD*6);

    gemm_qk<<<dim3(24, 32), 256, 0, stream>>>(X, W, bias, Qb, Kt);
    vmixt<<<512, 256, 0, stream>>>(XT, vtmp, Vt);
    attn8p<<<768, 256, 0, stream>>>(Qb, Kt, Vt, Yb);
    projmix<<<1024, 256, 0, stream>>>(Yb, ptmp, Out);
}